// Round 3
// baseline (574.472 us; speedup 1.0000x reference)
//
#include <hip/hip_runtime.h>
#include <stdint.h>

typedef unsigned short u16;

#define DIM 512
#define HIDN 1024
#define TT 4096
#define BB 8
#define MM 32768   // BB*TT
#define CH 128     // scan chunks
#define CL 32      // chunk length (CH*CL == TT)

// ---------- bf16 helpers ----------
__device__ __forceinline__ u16 f2bf(float f) {
  union { float f; uint32_t u; } v; v.f = f;
  uint32_t u = v.u;
  uint32_t r = u + 0x7fffu + ((u >> 16) & 1u);   // RTNE
  return (u16)(r >> 16);
}
__device__ __forceinline__ float bf2f(u16 h) {
  union { uint32_t u; float f; } v; v.u = ((uint32_t)h) << 16; return v.f;
}

typedef __bf16 bf16x8 __attribute__((ext_vector_type(8)));
typedef float f32x4 __attribute__((ext_vector_type(4)));

// ---------- prep: weights -> bf16, decay -> a/(1-a)/a^CL, convw -> [5][D] ----------
__global__ __launch_bounds__(256) void prep_kernel(
    const float* __restrict__ wout, const float* __restrict__ w1,
    const float* __restrict__ w2, const float* __restrict__ dl,
    const float* __restrict__ convw,
    u16* __restrict__ wout_h, u16* __restrict__ w1_h, u16* __restrict__ w2_h,
    float* __restrict__ a, float* __restrict__ oma, float* __restrict__ aL,
    float* __restrict__ convwT) {
  int i = blockIdx.x * 256 + threadIdx.x;
  if (i < DIM * DIM) wout_h[i] = f2bf(wout[i]);
  if (i < HIDN * DIM) { w1_h[i] = f2bf(w1[i]); w2_h[i] = f2bf(w2[i]); }
  if (i < 5 * DIM) {
    int kk = i / DIM, n = i - kk * DIM;
    convwT[i] = convw[n * 5 + kk];
  }
  if (i < DIM) {
    float av = 1.0f / (1.0f + expf(-dl[i]));
    a[i] = av; oma[i] = 1.0f - av; aL[i] = powf(av, (float)CL);
  }
}

// ---------- LayerNorm rows: fp32 in -> bf16 out (one wave per row) ----------
__global__ __launch_bounds__(256) void ln_rows(
    const float* __restrict__ xin, const float* __restrict__ g,
    const float* __restrict__ bvec, u16* __restrict__ out) {
  int lane = threadIdx.x & 63, wave = threadIdx.x >> 6;
  size_t row = (size_t)blockIdx.x * 4 + wave;
  const float4* xr = (const float4*)(xin + row * DIM);
  float4 v0 = xr[lane * 2 + 0];
  float4 v1 = xr[lane * 2 + 1];
  float s1 = v0.x + v0.y + v0.z + v0.w + v1.x + v1.y + v1.z + v1.w;
  float s2 = v0.x * v0.x + v0.y * v0.y + v0.z * v0.z + v0.w * v0.w
           + v1.x * v1.x + v1.y * v1.y + v1.z * v1.z + v1.w * v1.w;
#pragma unroll
  for (int o = 1; o < 64; o <<= 1) { s1 += __shfl_xor(s1, o); s2 += __shfl_xor(s2, o); }
  float mu = s1 * (1.0f / DIM);
  float var = s2 * (1.0f / DIM) - mu * mu;
  float rs = rsqrtf(var + 1e-5f);
  const float4* gr = (const float4*)g;
  const float4* br = (const float4*)bvec;
  float4 g0 = gr[lane * 2], g1 = gr[lane * 2 + 1];
  float4 b0 = br[lane * 2], b1 = br[lane * 2 + 1];
  uint32_t p0 = (uint32_t)f2bf((v0.x - mu) * rs * g0.x + b0.x) | ((uint32_t)f2bf((v0.y - mu) * rs * g0.y + b0.y) << 16);
  uint32_t p1 = (uint32_t)f2bf((v0.z - mu) * rs * g0.z + b0.z) | ((uint32_t)f2bf((v0.w - mu) * rs * g0.w + b0.w) << 16);
  uint32_t p2 = (uint32_t)f2bf((v1.x - mu) * rs * g1.x + b1.x) | ((uint32_t)f2bf((v1.y - mu) * rs * g1.y + b1.y) << 16);
  uint32_t p3 = (uint32_t)f2bf((v1.z - mu) * rs * g1.z + b1.z) | ((uint32_t)f2bf((v1.w - mu) * rs * g1.w + b1.w) << 16);
  uint4 pk; pk.x = p0; pk.y = p1; pk.z = p2; pk.w = p3;
  ((uint4*)(out + row * DIM))[lane] = pk;
}

// ---------- scan phase A: per-chunk local end states (2 channels/thread) ----------
__global__ __launch_bounds__(256) void scan_local(
    const u16* __restrict__ xn, const float* __restrict__ a,
    const float* __restrict__ oma, float* __restrict__ carry) {
  int idx = blockIdx.x * 256 + threadIdx.x;     // [b(3) | c(7) | dp(8)]
  int dp = (idx & 255) * 2;
  int c = (idx >> 8) & (CH - 1);
  int b = idx >> 15;
  float a0 = a[dp], a1 = a[dp + 1], o0 = oma[dp], o1 = oma[dp + 1];
  const uint32_t* xp = (const uint32_t*)(xn + ((size_t)(b * TT + c * CL)) * DIM + dp);
  float s0 = 0.f, s1 = 0.f;
#pragma unroll
  for (int i = 0; i < CL; ++i) {
    uint32_t u = xp[(size_t)i * (DIM / 2)];
    s0 = fmaf(a0, s0, o0 * bf2f((u16)(u & 0xffffu)));
    s1 = fmaf(a1, s1, o1 * bf2f((u16)(u >> 16)));
  }
  float2 cv; cv.x = s0; cv.y = s1;
  *(float2*)&carry[((size_t)(b * CH + c)) * DIM + dp] = cv;
}

// ---------- scan phase B: sequential scan over chunk carries ----------
__global__ __launch_bounds__(256) void scan_carry(
    const float* __restrict__ carry, const float* __restrict__ aL,
    float* __restrict__ start) {
  int idx = blockIdx.x * 256 + threadIdx.x;     // 0..4095: [b(3) | d(9)]
  int d = idx & (DIM - 1);
  int b = idx >> 9;
  float al = aL[d];
  float s = 0.f;
#pragma unroll 8
  for (int c = 0; c < CH; ++c) {
    size_t o = ((size_t)(b * CH + c)) * DIM + d;
    start[o] = s;
    s = fmaf(al, s, carry[o]);
  }
}

// ---------- scan phase C: replay with correct init, emit ss (2 channels/thread) ----------
__global__ __launch_bounds__(256) void scan_emit(
    const u16* __restrict__ xn, const float* __restrict__ a,
    const float* __restrict__ oma, const float* __restrict__ start,
    u16* __restrict__ ss) {
  int idx = blockIdx.x * 256 + threadIdx.x;     // [b(3) | c(7) | dp(8)]
  int dp = (idx & 255) * 2;
  int c = (idx >> 8) & (CH - 1);
  int b = idx >> 15;
  float a0 = a[dp], a1 = a[dp + 1], o0 = oma[dp], o1 = oma[dp + 1];
  const uint32_t* xp = (const uint32_t*)(xn + ((size_t)(b * TT + c * CL)) * DIM + dp);
  uint32_t* sp = (uint32_t*)(ss + ((size_t)(b * TT + c * CL)) * DIM + dp);
  float2 st = *(const float2*)&start[((size_t)(b * CH + c)) * DIM + dp];
  float s0 = st.x, s1 = st.y;
#pragma unroll
  for (int i = 0; i < CL; ++i) {
    uint32_t u = xp[(size_t)i * (DIM / 2)];
    s0 = fmaf(a0, s0, o0 * bf2f((u16)(u & 0xffffu)));
    s1 = fmaf(a1, s1, o1 * bf2f((u16)(u >> 16)));
    sp[(size_t)i * (DIM / 2)] = (uint32_t)f2bf(s0) | ((uint32_t)f2bf(s1) << 16);
  }
}

// ---------- direct-from-global bf16 MFMA GEMM, C[m,n] = sum_k A[m,k]*B[n,k] ----------
// No LDS, no barriers. Fragments load straight from global (16B bf16x8, K-contiguous),
// register double-buffered so loads for k-step n+1 are in flight during MFMAs of step n
// (compiler emits s_waitcnt vmcnt(16), never 0). B (weights) is L2-resident; A streams L3/HBM.
// Operands SWAPPED in the mfma call so acc holds per lane m=rA, n=q*4+r -> float4 epilogue.
// EPI 0: out_f32 = acc + bias[n] + depthwise_conv(xn)[m,n] + convb[n] + resid[m,n]  (-> x1)
// EPI 1: out_bf16 = gelu_exact(acc + bias[n])                                       (-> hg)
// EPI 2: out_f32 = acc + bias[n] + resid[m,n]                                       (-> d_out)
template <int Kd, int EPI>
__global__ __launch_bounds__(256, 3) void gemm_bt(
    const u16* __restrict__ A, const u16* __restrict__ Bmat,
    const float* __restrict__ bias, const float* __restrict__ resid,
    const u16* __restrict__ xn, const float* __restrict__ convwT,
    const float* __restrict__ convb, float* __restrict__ outf,
    u16* __restrict__ outh) {
  const int tid = threadIdx.x;
  const int lane = tid & 63, wave = tid >> 6;
  const int wr = (wave >> 1) * 64, wc = (wave & 1) * 64;
  const int rA = lane & 15, q = lane >> 4;

  const size_t rowTile = (size_t)blockIdx.y * 128;
  const size_t colTile = (size_t)blockIdx.x * 128;
  const u16* pA = A + (rowTile + wr + rA) * Kd + q * 8;
  const u16* pB = Bmat + (colTile + wc + rA) * Kd + q * 8;

  f32x4 acc[4][4];
#pragma unroll
  for (int i = 0; i < 4; i++)
#pragma unroll
    for (int j = 0; j < 4; j++) acc[i][j] = (f32x4){0.f, 0.f, 0.f, 0.f};

  bf16x8 a0[4], b0[4], a1[4], b1[4];
#pragma unroll
  for (int mi = 0; mi < 4; ++mi) a0[mi] = *(const bf16x8*)(pA + (size_t)mi * 16 * Kd);
#pragma unroll
  for (int ni = 0; ni < 4; ++ni) b0[ni] = *(const bf16x8*)(pB + (size_t)ni * 16 * Kd);

#pragma unroll 1
  for (int kt = 0; kt < Kd; kt += 64) {
#pragma unroll
    for (int mi = 0; mi < 4; ++mi) a1[mi] = *(const bf16x8*)(pA + (size_t)mi * 16 * Kd + kt + 32);
#pragma unroll
    for (int ni = 0; ni < 4; ++ni) b1[ni] = *(const bf16x8*)(pB + (size_t)ni * 16 * Kd + kt + 32);
#pragma unroll
    for (int mi = 0; mi < 4; ++mi)
#pragma unroll
      for (int ni = 0; ni < 4; ++ni)
        acc[mi][ni] = __builtin_amdgcn_mfma_f32_16x16x32_bf16(b0[ni], a0[mi], acc[mi][ni], 0, 0, 0);
    if (kt + 64 < Kd) {
#pragma unroll
      for (int mi = 0; mi < 4; ++mi) a0[mi] = *(const bf16x8*)(pA + (size_t)mi * 16 * Kd + kt + 64);
#pragma unroll
      for (int ni = 0; ni < 4; ++ni) b0[ni] = *(const bf16x8*)(pB + (size_t)ni * 16 * Kd + kt + 64);
    }
#pragma unroll
    for (int mi = 0; mi < 4; ++mi)
#pragma unroll
      for (int ni = 0; ni < 4; ++ni)
        acc[mi][ni] = __builtin_amdgcn_mfma_f32_16x16x32_bf16(b1[ni], a1[mi], acc[mi][ni], 0, 0, 0);
  }

  // ---- vectorized epilogue: lane owns (m, n0..n0+3) ----
#pragma unroll
  for (int mi = 0; mi < 4; ++mi) {
    size_t m = rowTile + wr + mi * 16 + rA;
#pragma unroll
    for (int ni = 0; ni < 4; ++ni) {
      int n0 = (int)colTile + wc + ni * 16 + q * 4;
      f32x4 v = acc[mi][ni];
      float4 bv = *(const float4*)&bias[n0];
      float val0 = v[0] + bv.x, val1 = v[1] + bv.y, val2 = v[2] + bv.z, val3 = v[3] + bv.w;
      if constexpr (EPI == 0) {
        int t = (int)(m & (TT - 1));
        float4 cb = *(const float4*)&convb[n0];
        float4 rv = *(const float4*)&resid[m * DIM + n0];
        val0 += cb.x + rv.x; val1 += cb.y + rv.y; val2 += cb.z + rv.z; val3 += cb.w + rv.w;
#pragma unroll
        for (int kk = 0; kk < 5; ++kk) {
          int ttc = t + kk - 2;
          if (ttc >= 0 && ttc < TT) {
            uint2 xv = *(const uint2*)&xn[(m + (size_t)kk - 2) * DIM + n0];
            float4 wv = *(const float4*)&convwT[kk * DIM + n0];
            val0 = fmaf(wv.x, bf2f((u16)(xv.x & 0xffffu)), val0);
            val1 = fmaf(wv.y, bf2f((u16)(xv.x >> 16)), val1);
            val2 = fmaf(wv.z, bf2f((u16)(xv.y & 0xffffu)), val2);
            val3 = fmaf(wv.w, bf2f((u16)(xv.y >> 16)), val3);
          }
        }
        float4 ov; ov.x = val0; ov.y = val1; ov.z = val2; ov.w = val3;
        *(float4*)&outf[m * DIM + n0] = ov;
      } else if constexpr (EPI == 1) {
        const float isq2 = 0.70710678118654752f;
        float g0 = 0.5f * val0 * (1.0f + erff(val0 * isq2));
        float g1 = 0.5f * val1 * (1.0f + erff(val1 * isq2));
        float g2 = 0.5f * val2 * (1.0f + erff(val2 * isq2));
        float g3 = 0.5f * val3 * (1.0f + erff(val3 * isq2));
        uint2 pk;
        pk.x = (uint32_t)f2bf(g0) | ((uint32_t)f2bf(g1) << 16);
        pk.y = (uint32_t)f2bf(g2) | ((uint32_t)f2bf(g3) << 16);
        *(uint2*)&outh[m * HIDN + n0] = pk;
      } else {
        float4 rv = *(const float4*)&resid[m * DIM + n0];
        float4 ov;
        ov.x = val0 + rv.x; ov.y = val1 + rv.y; ov.z = val2 + rv.z; ov.w = val3 + rv.w;
        *(float4*)&outf[m * DIM + n0] = ov;
      }
    }
  }
}

extern "C" void kernel_launch(void* const* d_in, const int* in_sizes, int n_in,
                              void* d_out, int out_size, void* d_ws, size_t ws_size,
                              hipStream_t stream) {
  const float* x      = (const float*)d_in[0];
  const float* dl     = (const float*)d_in[1];
  const float* W_out  = (const float*)d_in[2];
  const float* b_out  = (const float*)d_in[3];
  const float* conv_w = (const float*)d_in[4];
  const float* conv_b = (const float*)d_in[5];
  const float* ln1_g  = (const float*)d_in[6];
  const float* ln1_b  = (const float*)d_in[7];
  const float* ln2_g  = (const float*)d_in[8];
  const float* ln2_b  = (const float*)d_in[9];
  const float* W1     = (const float*)d_in[10];
  const float* b1     = (const float*)d_in[11];
  const float* W2     = (const float*)d_in[12];
  const float* b2     = (const float*)d_in[13];

  char* ws = (char*)d_ws;
  // small region (< 8 MiB)
  u16*   wout_h = (u16*)(ws + 0);                         // 512 KiB
  u16*   w1_h   = (u16*)(ws + 524288);                    // 1 MiB
  u16*   w2_h   = (u16*)(ws + 1572864);                   // 1 MiB
  float* a_buf  = (float*)(ws + 2621440);                 // 2 KiB
  float* oma    = (float*)(ws + 2623488);                 // 2 KiB
  float* aL     = (float*)(ws + 2625536);                 // 2 KiB
  float* convwT = (float*)(ws + 2627584);                 // 10 KiB
  float* carry  = (float*)(ws + (4u << 20));              // 2 MiB
  float* start  = (float*)(ws + 6291456);                 // 2 MiB
  // big regions
  u16*   xn  = (u16*)(ws + (8u << 20));                   // 32 MiB
  u16*   ssb = (u16*)(ws + (40u << 20));                  // 32 MiB
  float* x1  = (float*)(ws + (72u << 20));                // 64 MiB
  u16*   h   = (u16*)(ws + (136u << 20));                 // 32 MiB
  u16*   hg  = (u16*)(ws + (168u << 20));                 // 64 MiB

  float* out = (float*)d_out;

  prep_kernel<<<2048, 256, 0, stream>>>(W_out, W1, W2, dl, conv_w, wout_h, w1_h, w2_h, a_buf, oma, aL, convwT);
  ln_rows<<<MM / 4, 256, 0, stream>>>(x, ln1_g, ln1_b, xn);
  scan_local<<<(BB * CH * DIM / 2) / 256, 256, 0, stream>>>(xn, a_buf, oma, carry);
  scan_carry<<<(BB * DIM) / 256, 256, 0, stream>>>(carry, aL, start);
  scan_emit<<<(BB * CH * DIM / 2) / 256, 256, 0, stream>>>(xn, a_buf, oma, start, ssb);
  gemm_bt<512, 0><<<dim3(4, MM / 128), 256, 0, stream>>>(ssb, wout_h, b_out, x, xn, convwT, conv_b, x1, nullptr);
  ln_rows<<<MM / 4, 256, 0, stream>>>(x1, ln2_g, ln2_b, h);
  gemm_bt<512, 1><<<dim3(8, MM / 128), 256, 0, stream>>>(h, w1_h, b1, nullptr, nullptr, nullptr, nullptr, nullptr, hg);
  gemm_bt<1024, 2><<<dim3(4, MM / 128), 256, 0, stream>>>(hg, w2_h, b2, x1, nullptr, nullptr, nullptr, out, nullptr);
}

// Round 4
// 391.939 us; speedup vs baseline: 1.4657x; 1.4657x over previous
//
#include <hip/hip_runtime.h>
#include <stdint.h>

typedef unsigned short u16;

#define DIM 512
#define HIDN 1024
#define TT 4096
#define BB 8
#define MM 32768   // BB*TT
#define CH 128     // scan chunks
#define CL 32      // chunk length (CH*CL == TT)

// ---------- bf16 helpers ----------
__device__ __forceinline__ u16 f2bf(float f) {
  union { float f; uint32_t u; } v; v.f = f;
  uint32_t u = v.u;
  uint32_t r = u + 0x7fffu + ((u >> 16) & 1u);   // RTNE
  return (u16)(r >> 16);
}
__device__ __forceinline__ float bf2f(u16 h) {
  union { uint32_t u; float f; } v; v.u = ((uint32_t)h) << 16; return v.f;
}

typedef __bf16 bf16x8 __attribute__((ext_vector_type(8)));
typedef float f32x4 __attribute__((ext_vector_type(4)));

// ---------- prep: weights -> bf16, decay -> a/(1-a)/a^CL, convw -> [5][D] ----------
__global__ __launch_bounds__(256) void prep_kernel(
    const float* __restrict__ wout, const float* __restrict__ w1,
    const float* __restrict__ w2, const float* __restrict__ dl,
    const float* __restrict__ convw,
    u16* __restrict__ wout_h, u16* __restrict__ w1_h, u16* __restrict__ w2_h,
    float* __restrict__ a, float* __restrict__ oma, float* __restrict__ aL,
    float* __restrict__ convwT) {
  int i = blockIdx.x * 256 + threadIdx.x;
  if (i < DIM * DIM) wout_h[i] = f2bf(wout[i]);
  if (i < HIDN * DIM) { w1_h[i] = f2bf(w1[i]); w2_h[i] = f2bf(w2[i]); }
  if (i < 5 * DIM) {
    int kk = i / DIM, n = i - kk * DIM;
    convwT[i] = convw[n * 5 + kk];
  }
  if (i < DIM) {
    float av = 1.0f / (1.0f + expf(-dl[i]));
    a[i] = av; oma[i] = 1.0f - av; aL[i] = powf(av, (float)CL);
  }
}

// ---------- LayerNorm rows: fp32 in -> bf16 out (one wave per row) ----------
__global__ __launch_bounds__(256) void ln_rows(
    const float* __restrict__ xin, const float* __restrict__ g,
    const float* __restrict__ bvec, u16* __restrict__ out) {
  int lane = threadIdx.x & 63, wave = threadIdx.x >> 6;
  size_t row = (size_t)blockIdx.x * 4 + wave;
  const float4* xr = (const float4*)(xin + row * DIM);
  float4 v0 = xr[lane * 2 + 0];
  float4 v1 = xr[lane * 2 + 1];
  float s1 = v0.x + v0.y + v0.z + v0.w + v1.x + v1.y + v1.z + v1.w;
  float s2 = v0.x * v0.x + v0.y * v0.y + v0.z * v0.z + v0.w * v0.w
           + v1.x * v1.x + v1.y * v1.y + v1.z * v1.z + v1.w * v1.w;
#pragma unroll
  for (int o = 1; o < 64; o <<= 1) { s1 += __shfl_xor(s1, o); s2 += __shfl_xor(s2, o); }
  float mu = s1 * (1.0f / DIM);
  float var = s2 * (1.0f / DIM) - mu * mu;
  float rs = rsqrtf(var + 1e-5f);
  const float4* gr = (const float4*)g;
  const float4* br = (const float4*)bvec;
  float4 g0 = gr[lane * 2], g1 = gr[lane * 2 + 1];
  float4 b0 = br[lane * 2], b1 = br[lane * 2 + 1];
  uint32_t p0 = (uint32_t)f2bf((v0.x - mu) * rs * g0.x + b0.x) | ((uint32_t)f2bf((v0.y - mu) * rs * g0.y + b0.y) << 16);
  uint32_t p1 = (uint32_t)f2bf((v0.z - mu) * rs * g0.z + b0.z) | ((uint32_t)f2bf((v0.w - mu) * rs * g0.w + b0.w) << 16);
  uint32_t p2 = (uint32_t)f2bf((v1.x - mu) * rs * g1.x + b1.x) | ((uint32_t)f2bf((v1.y - mu) * rs * g1.y + b1.y) << 16);
  uint32_t p3 = (uint32_t)f2bf((v1.z - mu) * rs * g1.z + b1.z) | ((uint32_t)f2bf((v1.w - mu) * rs * g1.w + b1.w) << 16);
  uint4 pk; pk.x = p0; pk.y = p1; pk.z = p2; pk.w = p3;
  ((uint4*)(out + row * DIM))[lane] = pk;
}

// ---------- scan phase A: per-chunk local end states (2 channels/thread) ----------
__global__ __launch_bounds__(256) void scan_local(
    const u16* __restrict__ xn, const float* __restrict__ a,
    const float* __restrict__ oma, float* __restrict__ carry) {
  int idx = blockIdx.x * 256 + threadIdx.x;     // [b(3) | c(7) | dp(8)]
  int dp = (idx & 255) * 2;
  int c = (idx >> 8) & (CH - 1);
  int b = idx >> 15;
  float a0 = a[dp], a1 = a[dp + 1], o0 = oma[dp], o1 = oma[dp + 1];
  const uint32_t* xp = (const uint32_t*)(xn + ((size_t)(b * TT + c * CL)) * DIM + dp);
  float s0 = 0.f, s1 = 0.f;
#pragma unroll
  for (int i = 0; i < CL; ++i) {
    uint32_t u = xp[(size_t)i * (DIM / 2)];
    s0 = fmaf(a0, s0, o0 * bf2f((u16)(u & 0xffffu)));
    s1 = fmaf(a1, s1, o1 * bf2f((u16)(u >> 16)));
  }
  float2 cv; cv.x = s0; cv.y = s1;
  *(float2*)&carry[((size_t)(b * CH + c)) * DIM + dp] = cv;
}

// ---------- scan phase B: sequential scan over chunk carries ----------
__global__ __launch_bounds__(256) void scan_carry(
    const float* __restrict__ carry, const float* __restrict__ aL,
    float* __restrict__ start) {
  int idx = blockIdx.x * 256 + threadIdx.x;     // 0..4095: [b(3) | d(9)]
  int d = idx & (DIM - 1);
  int b = idx >> 9;
  float al = aL[d];
  float s = 0.f;
#pragma unroll 8
  for (int c = 0; c < CH; ++c) {
    size_t o = ((size_t)(b * CH + c)) * DIM + d;
    start[o] = s;
    s = fmaf(al, s, carry[o]);
  }
}

// ---------- scan phase C: replay with correct init, emit ss (2 channels/thread) ----------
__global__ __launch_bounds__(256) void scan_emit(
    const u16* __restrict__ xn, const float* __restrict__ a,
    const float* __restrict__ oma, const float* __restrict__ start,
    u16* __restrict__ ss) {
  int idx = blockIdx.x * 256 + threadIdx.x;     // [b(3) | c(7) | dp(8)]
  int dp = (idx & 255) * 2;
  int c = (idx >> 8) & (CH - 1);
  int b = idx >> 15;
  float a0 = a[dp], a1 = a[dp + 1], o0 = oma[dp], o1 = oma[dp + 1];
  const uint32_t* xp = (const uint32_t*)(xn + ((size_t)(b * TT + c * CL)) * DIM + dp);
  uint32_t* sp = (uint32_t*)(ss + ((size_t)(b * TT + c * CL)) * DIM + dp);
  float2 st = *(const float2*)&start[((size_t)(b * CH + c)) * DIM + dp];
  float s0 = st.x, s1 = st.y;
#pragma unroll
  for (int i = 0; i < CL; ++i) {
    uint32_t u = xp[(size_t)i * (DIM / 2)];
    s0 = fmaf(a0, s0, o0 * bf2f((u16)(u & 0xffffu)));
    s1 = fmaf(a1, s1, o1 * bf2f((u16)(u >> 16)));
    sp[(size_t)i * (DIM / 2)] = (uint32_t)f2bf(s0) | ((uint32_t)f2bf(s1) << 16);
  }
}

// ---------- tiled bf16 MFMA GEMM, C[m,n] = sum_k A[m,k]*B[n,k] ----------
// Double-buffered global_load_lds staging with RAW s_barrier + manual
// s_waitcnt vmcnt(8): next tile's 8 loads/wave (1 KiB each, wave-wide) stay
// in flight across the barrier while this tile computes — no vmcnt(0) drain.
// 1-D grid with XCD swizzle: rows partitioned across XCDs, all NCOL col-strips
// of a row-tile adjacent on one XCD -> A-strip fetched once per L2.
// Operands SWAPPED in mfma so acc holds per lane m=rA, n=q*4+r -> float4 epilogue.
// EPI 0: out_f32 = acc + bias[n] + depthwise_conv(xn)[m,n] + convb[n] + resid[m,n]  (-> x1)
// EPI 1: out_bf16 = gelu_exact(acc + bias[n])                                       (-> hg)
// EPI 2: out_f32 = acc + bias[n] + resid[m,n]                                       (-> d_out)
template <int Kd, int NCOL, int EPI>
__global__ __launch_bounds__(256) void gemm_bt(
    const u16* __restrict__ A, const u16* __restrict__ Bmat,
    const float* __restrict__ bias, const float* __restrict__ resid,
    const u16* __restrict__ xn, const float* __restrict__ convwT,
    const float* __restrict__ convb, float* __restrict__ outf,
    u16* __restrict__ outh) {
  __shared__ alignas(16) u16 sA[2][128 * 64];
  __shared__ alignas(16) u16 sB[2][128 * 64];
  const int tid = threadIdx.x;
  const int lane = tid & 63, wave = tid >> 6;
  const int wr = (wave >> 1) * 64, wc = (wave & 1) * 64;
  const int rA = lane & 15, q = lane >> 4;

  // XCD swizzle: lin%8 ~ XCD id; rows partitioned by XCD, cols fast-varying.
  const int lin = blockIdx.x;
  const int tile_col = (lin >> 3) & (NCOL - 1);
  const int tile_row = (lin & 7) + 8 * ((lin >> 3) / NCOL);
  const size_t rowTile = (size_t)tile_row * 128;
  const size_t colTile = (size_t)tile_col * 128;

  f32x4 acc[4][4];
#pragma unroll
  for (int i = 0; i < 4; i++)
#pragma unroll
    for (int j = 0; j < 4; j++) acc[i][j] = (f32x4){0.f, 0.f, 0.f, 0.f};

  const u16* Abase = A + rowTile * Kd;
  const u16* Bbase = Bmat + colTile * Kd;

  const int lrow = lane >> 3;               // 0..7 rows within an 8-row group
  const int lslot = lane & 7;               // 16B slot within row
  const int gk = ((lslot ^ lrow) & 7) * 8;  // XOR-swizzled k offset (elements)

  auto stage = [&](int kt, int buf) {
#pragma unroll
    for (int it = 0; it < 4; ++it) {
      const int m0 = (it * 4 + wave) * 8;
      const u16* ga = Abase + (size_t)(m0 + lrow) * Kd + kt + gk;
      const u16* gb = Bbase + (size_t)(m0 + lrow) * Kd + kt + gk;
      __builtin_amdgcn_global_load_lds(
          (const __attribute__((address_space(1))) void*)ga,
          (__attribute__((address_space(3))) void*)&sA[buf][m0 * 64], 16, 0, 0);
      __builtin_amdgcn_global_load_lds(
          (const __attribute__((address_space(1))) void*)gb,
          (__attribute__((address_space(3))) void*)&sB[buf][m0 * 64], 16, 0, 0);
    }
  };

  constexpr int NI = Kd / 64;
  stage(0, 0);
#pragma unroll 1
  for (int i = 0; i < NI; ++i) {
    // barrier 1: all waves finished compute(i-1) -> buf[(i+1)&1] is free.
    __asm__ __volatile__("s_barrier" ::: "memory");
    if (i + 1 < NI) {
      stage((i + 1) * 64, (i + 1) & 1);
      __asm__ __volatile__("s_waitcnt vmcnt(8)" ::: "memory");  // iter-i loads done; i+1 in flight
    } else {
      __asm__ __volatile__("s_waitcnt vmcnt(0)" ::: "memory");
    }
    // barrier 2: everyone's iter-i data landed in LDS.
    __asm__ __volatile__("s_barrier" ::: "memory");
    const u16* bufA = sA[i & 1];
    const u16* bufB = sB[i & 1];
#pragma unroll
    for (int ks = 0; ks < 2; ++ks) {
      bf16x8 af[4], bfr[4];
#pragma unroll
      for (int mi = 0; mi < 4; ++mi) {
        int r = wr + mi * 16 + rA;
        int pos = ((ks * 4 + q) ^ (r & 7));
        af[mi] = *(const bf16x8*)&bufA[r * 64 + pos * 8];
      }
#pragma unroll
      for (int ni = 0; ni < 4; ++ni) {
        int r = wc + ni * 16 + rA;
        int pos = ((ks * 4 + q) ^ (r & 7));
        bfr[ni] = *(const bf16x8*)&bufB[r * 64 + pos * 8];
      }
#pragma unroll
      for (int mi = 0; mi < 4; ++mi)
#pragma unroll
        for (int ni = 0; ni < 4; ++ni)
          acc[mi][ni] = __builtin_amdgcn_mfma_f32_16x16x32_bf16(bfr[ni], af[mi], acc[mi][ni], 0, 0, 0);
    }
  }

  // ---- vectorized epilogue: lane owns (m, n0..n0+3) ----
#pragma unroll
  for (int mi = 0; mi < 4; ++mi) {
    size_t m = rowTile + wr + mi * 16 + rA;
#pragma unroll
    for (int ni = 0; ni < 4; ++ni) {
      int n0 = (int)colTile + wc + ni * 16 + q * 4;
      f32x4 v = acc[mi][ni];
      float4 bv = *(const float4*)&bias[n0];
      float val0 = v[0] + bv.x, val1 = v[1] + bv.y, val2 = v[2] + bv.z, val3 = v[3] + bv.w;
      if constexpr (EPI == 0) {
        int t = (int)(m & (TT - 1));
        float4 cb = *(const float4*)&convb[n0];
        float4 rv = *(const float4*)&resid[m * DIM + n0];
        val0 += cb.x + rv.x; val1 += cb.y + rv.y; val2 += cb.z + rv.z; val3 += cb.w + rv.w;
#pragma unroll
        for (int kk = 0; kk < 5; ++kk) {
          int ttc = t + kk - 2;
          if (ttc >= 0 && ttc < TT) {
            uint2 xv = *(const uint2*)&xn[(m + (size_t)kk - 2) * DIM + n0];
            float4 wv = *(const float4*)&convwT[kk * DIM + n0];
            val0 = fmaf(wv.x, bf2f((u16)(xv.x & 0xffffu)), val0);
            val1 = fmaf(wv.y, bf2f((u16)(xv.x >> 16)), val1);
            val2 = fmaf(wv.z, bf2f((u16)(xv.y & 0xffffu)), val2);
            val3 = fmaf(wv.w, bf2f((u16)(xv.y >> 16)), val3);
          }
        }
        float4 ov; ov.x = val0; ov.y = val1; ov.z = val2; ov.w = val3;
        *(float4*)&outf[m * DIM + n0] = ov;
      } else if constexpr (EPI == 1) {
        const float isq2 = 0.70710678118654752f;
        float g0 = 0.5f * val0 * (1.0f + erff(val0 * isq2));
        float g1 = 0.5f * val1 * (1.0f + erff(val1 * isq2));
        float g2 = 0.5f * val2 * (1.0f + erff(val2 * isq2));
        float g3 = 0.5f * val3 * (1.0f + erff(val3 * isq2));
        uint2 pk;
        pk.x = (uint32_t)f2bf(g0) | ((uint32_t)f2bf(g1) << 16);
        pk.y = (uint32_t)f2bf(g2) | ((uint32_t)f2bf(g3) << 16);
        *(uint2*)&outh[m * HIDN + n0] = pk;
      } else {
        float4 rv = *(const float4*)&resid[m * DIM + n0];
        float4 ov;
        ov.x = val0 + rv.x; ov.y = val1 + rv.y; ov.z = val2 + rv.z; ov.w = val3 + rv.w;
        *(float4*)&outf[m * DIM + n0] = ov;
      }
    }
  }
}

extern "C" void kernel_launch(void* const* d_in, const int* in_sizes, int n_in,
                              void* d_out, int out_size, void* d_ws, size_t ws_size,
                              hipStream_t stream) {
  const float* x      = (const float*)d_in[0];
  const float* dl     = (const float*)d_in[1];
  const float* W_out  = (const float*)d_in[2];
  const float* b_out  = (const float*)d_in[3];
  const float* conv_w = (const float*)d_in[4];
  const float* conv_b = (const float*)d_in[5];
  const float* ln1_g  = (const float*)d_in[6];
  const float* ln1_b  = (const float*)d_in[7];
  const float* ln2_g  = (const float*)d_in[8];
  const float* ln2_b  = (const float*)d_in[9];
  const float* W1     = (const float*)d_in[10];
  const float* b1     = (const float*)d_in[11];
  const float* W2     = (const float*)d_in[12];
  const float* b2     = (const float*)d_in[13];

  char* ws = (char*)d_ws;
  // small region (< 8 MiB)
  u16*   wout_h = (u16*)(ws + 0);                         // 512 KiB
  u16*   w1_h   = (u16*)(ws + 524288);                    // 1 MiB
  u16*   w2_h   = (u16*)(ws + 1572864);                   // 1 MiB
  float* a_buf  = (float*)(ws + 2621440);                 // 2 KiB
  float* oma    = (float*)(ws + 2623488);                 // 2 KiB
  float* aL     = (float*)(ws + 2625536);                 // 2 KiB
  float* convwT = (float*)(ws + 2627584);                 // 10 KiB
  float* carry  = (float*)(ws + (4u << 20));              // 2 MiB
  float* start  = (float*)(ws + 6291456);                 // 2 MiB
  // big regions
  u16*   xn  = (u16*)(ws + (8u << 20));                   // 32 MiB
  u16*   ssb = (u16*)(ws + (40u << 20));                  // 32 MiB
  float* x1  = (float*)(ws + (72u << 20));                // 64 MiB
  u16*   h   = (u16*)(ws + (136u << 20));                 // 32 MiB
  u16*   hg  = (u16*)(ws + (168u << 20));                 // 64 MiB

  float* out = (float*)d_out;

  prep_kernel<<<2048, 256, 0, stream>>>(W_out, W1, W2, dl, conv_w, wout_h, w1_h, w2_h, a_buf, oma, aL, convwT);
  ln_rows<<<MM / 4, 256, 0, stream>>>(x, ln1_g, ln1_b, xn);
  scan_local<<<(BB * CH * DIM / 2) / 256, 256, 0, stream>>>(xn, a_buf, oma, carry);
  scan_carry<<<(BB * DIM) / 256, 256, 0, stream>>>(carry, aL, start);
  scan_emit<<<(BB * CH * DIM / 2) / 256, 256, 0, stream>>>(xn, a_buf, oma, start, ssb);
  gemm_bt<512, 4, 0><<<1024, 256, 0, stream>>>(ssb, wout_h, b_out, x, xn, convwT, conv_b, x1, nullptr);
  ln_rows<<<MM / 4, 256, 0, stream>>>(x1, ln2_g, ln2_b, h);
  gemm_bt<512, 8, 1><<<2048, 256, 0, stream>>>(h, w1_h, b1, nullptr, nullptr, nullptr, nullptr, nullptr, hg);
  gemm_bt<1024, 4, 2><<<1024, 256, 0, stream>>>(hg, w2_h, b2, x1, nullptr, nullptr, nullptr, out, nullptr);
}